// Round 3
// baseline (1749.157 us; speedup 1.0000x reference)
//
#include <hip/hip_runtime.h>
#include <hip/hip_cooperative_groups.h>
#include <math.h>

namespace cg = cooperative_groups;

#define EMBED  1024
#define HIDDEN 1024
#define VOCAB  32000
#define TSTEPS 64
#define G4     4096   // 4*HIDDEN
#define NBLK   256    // lstm blocks (1 per CU, cooperative-resident)

// ---------------------------------------------------------------------------
// Kernel 1: build xs[t] = (t==0 ? features : embed_table[captions[t-1]])
// ---------------------------------------------------------------------------
__global__ void build_xs(const int* __restrict__ caps,
                         const float* __restrict__ feat,
                         const float* __restrict__ table,
                         float* __restrict__ xs) {
    int t = blockIdx.x;
    int e = threadIdx.x + blockIdx.y * 256;
    float v;
    if (t == 0) {
        v = feat[e];
    } else {
        size_t row = (size_t)caps[t - 1];
        v = table[row * EMBED + e];
    }
    xs[(size_t)t * EMBED + e] = v;
}

// ---------------------------------------------------------------------------
// Kernel 2: Xg[t][j] = dot(xs[t], W_ih[j]) + b_ih[j] + b_hh[j]
// LDS-staged W tile -> coalesced global loads. 256 blocks x 16 j-rows.
// ---------------------------------------------------------------------------
__global__ __launch_bounds__(256) void xg_gemm(const float* __restrict__ xs,
                                               const float* __restrict__ Wih,
                                               const float* __restrict__ bih,
                                               const float* __restrict__ bhh,
                                               float* __restrict__ Xg) {
    __shared__ float xs_s[64][132];   // +4 pad
    __shared__ float Ws[16][136];     // +8 pad -> 2-way max on reads
    int tid = threadIdx.x;
    int jl  = tid & 15;
    int tg  = tid >> 4;               // t_base = tg*4
    int j   = blockIdx.x * 16 + jl;
    float acc[4] = {0.f, 0.f, 0.f, 0.f};

    for (int c = 0; c < 8; ++c) {
        __syncthreads();
        for (int idx = tid; idx < 64 * 32; idx += 256) {
            int r = idx >> 5, f = idx & 31;
            float4 v = ((const float4*)(xs + (size_t)r * EMBED + c * 128))[f];
            *((float4*)&xs_s[r][f * 4]) = v;
        }
        for (int idx = tid; idx < 16 * 32; idx += 256) {
            int r = idx >> 5, f = idx & 31;
            float4 w = ((const float4*)(Wih + (size_t)(blockIdx.x * 16 + r) * EMBED + c * 128))[f];
            *((float4*)&Ws[r][f * 4]) = w;
        }
        __syncthreads();
        for (int f = 0; f < 32; ++f) {
            float4 w = *((const float4*)&Ws[jl][f * 4]);
#pragma unroll
            for (int k = 0; k < 4; ++k) {
                const float* xr = &xs_s[tg * 4 + k][f * 4];
                acc[k] += w.x * xr[0] + w.y * xr[1] + w.z * xr[2] + w.w * xr[3];
            }
        }
    }
    float bias = bih[j] + bhh[j];
#pragma unroll
    for (int k = 0; k < 4; ++k) {
        Xg[(size_t)(tg * 4 + k) * G4 + j] = acc[k] + bias;
    }
}

// ---------------------------------------------------------------------------
// Kernel 3: sequential LSTM, 256 blocks x 256 threads, cooperative launch
// (co-residency only). Grid barrier = per-block release flag + parallel
// flag-vector spin (no atomic RMW serialization). W_hh slice pinned in VGPRs
// via asm memory clobber. h exchanged via agent-scope atomics (per-XCD L2s
// are non-coherent).
// ---------------------------------------------------------------------------
__global__ __launch_bounds__(256, 1) void lstm_seq(const float* __restrict__ Xg,
                                                   const float* __restrict__ Whh,
                                                   float* hbuf,        // 2*1024 f, zeroed
                                                   float* __restrict__ hs,
                                                   unsigned* flags) {  // NBLK, zeroed
    __shared__ float h_s[HIDDEN];
    __shared__ float gate_s[4][4];

    int tid  = threadIdx.x;
    int lane = tid & 63;
    int wv   = tid >> 6;          // gate index 0..3 (i,f,g,o)
    int q    = lane >> 4;         // 0..3
    int c16  = lane & 15;
    int q0   = blockIdx.x * 4;
    int row  = wv * HIDDEN + q0 + q;
    const float4* wrow = (const float4*)(Whh + (size_t)row * HIDDEN);

    // Pin this lane's 64-float W_hh slice in VGPRs. The memory-clobber asm
    // forbids sinking these loads into the loop (R1: compiler re-fetched
    // every step, VGPR_Count=48 proved wreg never materialized).
    float4 wreg[16];
#pragma unroll
    for (int k = 0; k < 16; ++k) wreg[k] = wrow[c16 + 16 * k];
    asm volatile("" ::: "memory");

    float cstate = 0.0f;          // live in tid<4 only
    float* hprev = hbuf;          // zero-initialized by memset
    float* hnext = hbuf + HIDDEN;

    for (int t = 0; t < TSTEPS; ++t) {
        // Prefetch this step's input-side gates (independent of h) so the
        // loads issue before the barrier spin.
        float xgi = 0.f, xgf = 0.f, xgg = 0.f, xgo = 0.f;
        if (tid < 4) {
            const float* xg = Xg + (size_t)t * G4;
            int hj = q0 + tid;
            xgi = xg[hj];
            xgf = xg[HIDDEN + hj];
            xgg = xg[2 * HIDDEN + hj];
            xgo = xg[3 * HIDDEN + hj];
        }

        // ---- wait until every block has published step t-1 (flags >= t)
        if (t > 0) {
            unsigned tgt = (unsigned)t;
            while (__syncthreads_count(
                       __hip_atomic_load(&flags[tid], __ATOMIC_RELAXED,
                                         __HIP_MEMORY_SCOPE_AGENT) < tgt) != 0) {
            }
            __threadfence();   // acquire: order subsequent h loads
        }

        // stage h (agent-scope: bypass non-coherent L1/L2, read LLC)
        for (int i = tid; i < HIDDEN; i += 256) {
            h_s[i] = __hip_atomic_load(hprev + i, __ATOMIC_RELAXED,
                                       __HIP_MEMORY_SCOPE_AGENT);
        }
        __syncthreads();

        float sum = 0.f;
#pragma unroll
        for (int k = 0; k < 16; ++k) {
            float4 w = wreg[k];
            const float* hv = &h_s[(c16 + 16 * k) * 4];
            sum += w.x * hv[0] + w.y * hv[1] + w.z * hv[2] + w.w * hv[3];
        }
        sum += __shfl_xor(sum, 1);
        sum += __shfl_xor(sum, 2);
        sum += __shfl_xor(sum, 4);
        sum += __shfl_xor(sum, 8);
        if (c16 == 0) gate_s[wv][q] = sum;
        __syncthreads();

        if (tid < 4) {
            float gi = gate_s[0][tid] + xgi;
            float gf = gate_s[1][tid] + xgf;
            float gg = gate_s[2][tid] + xgg;
            float go = gate_s[3][tid] + xgo;
            float i_ = 1.f / (1.f + expf(-gi));
            float f_ = 1.f / (1.f + expf(-gf));
            float g_ = tanhf(gg);
            float o_ = 1.f / (1.f + expf(-go));
            cstate = f_ * cstate + i_ * g_;
            float hv = o_ * tanhf(cstate);
            int hj = q0 + tid;
            __hip_atomic_store(hnext + hj, hv, __ATOMIC_RELAXED,
                               __HIP_MEMORY_SCOPE_AGENT);
            hs[(size_t)t * HIDDEN + hj] = hv;
        }
        __syncthreads();   // drains vmcnt: h stores complete before flag

        if (tid == 0) {
            __hip_atomic_store(&flags[blockIdx.x], (unsigned)(t + 1),
                               __ATOMIC_RELEASE, __HIP_MEMORY_SCOPE_AGENT);
        }

        float* tmp = hprev; hprev = hnext; hnext = tmp;
    }
}

// ---------------------------------------------------------------------------
// Kernel 4: logits = hs @ fc_W.T + fc_b   [64,1024] x [1024,32000]
// LDS-staged W tile -> coalesced loads; compute-bound fp32 (~27 us floor).
// ---------------------------------------------------------------------------
__global__ __launch_bounds__(256) void logits_gemm(const float* __restrict__ hs,
                                                   const float* __restrict__ fcW,
                                                   const float* __restrict__ fcb,
                                                   float* __restrict__ out) {
    __shared__ float hs_s[64][132];   // 33.8 KB
    __shared__ float Ws[32][136];     // 17.4 KB, +8 pad -> 2-way max
    int tid = threadIdx.x;
    int vl  = tid & 31;
    int tg  = tid >> 5;               // t_base = tg*8
    int v   = blockIdx.x * 32 + vl;
    float acc[8] = {0.f, 0.f, 0.f, 0.f, 0.f, 0.f, 0.f, 0.f};

    for (int c = 0; c < 8; ++c) {
        __syncthreads();
        for (int idx = tid; idx < 64 * 32; idx += 256) {
            int r = idx >> 5, f = idx & 31;
            float4 h4 = ((const float4*)(hs + (size_t)r * HIDDEN + c * 128))[f];
            *((float4*)&hs_s[r][f * 4]) = h4;
        }
        for (int idx = tid; idx < 32 * 32; idx += 256) {
            int r = idx >> 5, f = idx & 31;
            float4 w = ((const float4*)(fcW + (size_t)(blockIdx.x * 32 + r) * HIDDEN + c * 128))[f];
            *((float4*)&Ws[r][f * 4]) = w;
        }
        __syncthreads();
        for (int f = 0; f < 32; ++f) {
            float4 w = *((const float4*)&Ws[vl][f * 4]);
#pragma unroll
            for (int k = 0; k < 8; ++k) {
                const float* hv = &hs_s[tg * 8 + k][f * 4];
                acc[k] += w.x * hv[0] + w.y * hv[1] + w.z * hv[2] + w.w * hv[3];
            }
        }
    }
    float b = fcb[v];
#pragma unroll
    for (int k = 0; k < 8; ++k) {
        out[(size_t)(tg * 8 + k) * VOCAB + v] = acc[k] + b;
    }
}

// ---------------------------------------------------------------------------
extern "C" void kernel_launch(void* const* d_in, const int* in_sizes, int n_in,
                              void* d_out, int out_size, void* d_ws, size_t ws_size,
                              hipStream_t stream) {
    const int*   caps  = (const int*)  d_in[0];
    const float* feat  = (const float*)d_in[1];
    const float* table = (const float*)d_in[2];
    const float* Wih   = (const float*)d_in[3];
    const float* Whh   = (const float*)d_in[4];
    const float* bih   = (const float*)d_in[5];
    const float* bhh   = (const float*)d_in[6];
    const float* fcW   = (const float*)d_in[7];
    const float* fcb   = (const float*)d_in[8];
    float* out = (float*)d_out;

    char* ws = (char*)d_ws;
    float*    xs    = (float*)(ws);                                  // 256 KB
    float*    Xg    = (float*)(ws + 262144);                         // 1 MB
    float*    hs    = (float*)(ws + 262144 + 1048576);               // 256 KB
    float*    hbuf  = (float*)(ws + 262144 + 1048576 + 262144);      // 8 KB
    unsigned* flags = (unsigned*)(ws + 262144 + 1048576 + 262144 + 8192); // 1 KB

    // ws is poisoned 0xAA before every timed call: zero h double-buffer+flags.
    hipMemsetAsync(hbuf, 0, 2 * HIDDEN * sizeof(float) + NBLK * sizeof(unsigned),
                   stream);

    build_xs<<<dim3(TSTEPS, 4), 256, 0, stream>>>(caps, feat, table, xs);
    xg_gemm <<<256, 256, 0, stream>>>(xs, Wih, bih, bhh, Xg);

    void* args[] = {(void*)&Xg, (void*)&Whh, (void*)&hbuf, (void*)&hs, (void*)&flags};
    hipLaunchCooperativeKernel(lstm_seq, dim3(NBLK), dim3(256), args, 0u, stream);

    logits_gemm<<<VOCAB / 32, 256, 0, stream>>>(hs, fcW, fcb, out);
}